// Round 9
// baseline (257.506 us; speedup 1.0000x reference)
//
#include <hip/hip_runtime.h>

#define SEQ   4096
#define EMB   1280
#define NH    16
#define HD    80
#define HDP   96
#define O3    3840
#define SEGLEN 1024
#define NSEG  4
// sqrt(80) * log2(e): scores computed in log2 domain -> softmax uses native v_exp_f32 (exp2)
#define QSCALE (8.94427190999915878564f * 1.44269504088896340736f)

typedef unsigned short u16;
typedef __attribute__((ext_vector_type(8))) _Float16 f16x8;
typedef __attribute__((ext_vector_type(4))) _Float16 f16x4;
typedef __attribute__((ext_vector_type(2))) __fp16   h16x2;
typedef __attribute__((ext_vector_type(4))) float    f32x4;

__device__ __forceinline__ float ex2(float x) { return __builtin_amdgcn_exp2f(x); }

__device__ __forceinline__ u16 f2h(float f) {
  union { _Float16 h; u16 u; } v; v.h = (_Float16)f; return v.u;
}
__device__ __forceinline__ float h2f(u16 b) {
  union { u16 u; _Float16 h; } v; v.u = b; return (float)v.h;
}
__device__ __forceinline__ f32x4 exp2_4(f32x4 x) {
  f32x4 r; r.x = ex2(x.x); r.y = ex2(x.y); r.z = ex2(x.z); r.w = ex2(x.w); return r;
}
__device__ __forceinline__ f16x4 pk4(f32x4 s) {
  union { h16x2 h[2]; f16x4 f; } u;
  u.h[0] = __builtin_amdgcn_cvt_pkrtz(s.x, s.y);
  u.h[1] = __builtin_amdgcn_cvt_pkrtz(s.z, s.w);
  return u.f;
}
// async global->LDS, 16B per lane. LDS dest must be wave-uniform base + lane*16.
__device__ __forceinline__ void gl2lds16(const u16* g, u16* l) {
  __builtin_amdgcn_global_load_lds(
      (const __attribute__((address_space(1))) unsigned int*)g,
      (__attribute__((address_space(3))) unsigned int*)l, 16, 0, 0);
}

// ---------------- fused fp32 -> fp16 convert for hs, w_qkv, w_proj ----------------
#define CVT_N1 (SEQ * EMB / 4)
#define CVT_N2 (O3 * EMB / 4)
#define CVT_N3 (EMB * EMB / 4)
__global__ void cvt_all_kernel(const float* __restrict__ a, const float* __restrict__ b,
                               const float* __restrict__ c, u16* __restrict__ oa,
                               u16* __restrict__ ob, u16* __restrict__ oc) {
  int i = blockIdx.x * blockDim.x + threadIdx.x;
  const float* src; u16* dst; int j = i;
  if (j < CVT_N1)                { src = a; dst = oa; }
  else if (j < CVT_N1 + CVT_N2)  { src = b; dst = ob; j -= CVT_N1; }
  else                           { src = c; dst = oc; j -= CVT_N1 + CVT_N2; }
  float4 f = ((const float4*)src)[j];
  union { u16 h[4]; uint2 v; } o;
  o.h[0] = f2h(f.x); o.h[1] = f2h(f.y); o.h[2] = f2h(f.z); o.h[3] = f2h(f.w);
  ((uint2*)dst)[j] = o.v;
}

// ---------------- fp16 MFMA GEMM (128x128 tile, 2-barrier) -- kept for proj ----------------
// XCD-chunked swizzle: grid must be divisible by 8 (proj: 10x32=320 -> 40 blocks/XCD,
// bm in [4x,4x+4) per XCD -> A-panel L2 locality).
template<int OUTF>
__global__ __launch_bounds__(256)
void gemm_bias_kernel(const u16* __restrict__ A, const u16* __restrict__ W,
                      const float* __restrict__ bias, void* __restrict__ Cout,
                      int N, int K) {
  __shared__ u16 As[128][64];
  __shared__ u16 Bs[128][64];
  const int tid  = threadIdx.x;
  const int flat = blockIdx.x + gridDim.x * blockIdx.y;
  const int cpx  = (gridDim.x * gridDim.y) >> 3;
  const int nid  = (flat & 7) * cpx + (flat >> 3);
  const int bm   = nid / gridDim.x, bn = nid % gridDim.x;
  const int lane = tid & 63;
  const int wid  = tid >> 6;
  const int wm   = (wid >> 1) * 64, wn = (wid & 1) * 64;
  const int lr   = lane & 15, quad = lane >> 4;

  f32x4 acc[4][4];
  const f32x4 z4 = {0.f, 0.f, 0.f, 0.f};
  #pragma unroll
  for (int i = 0; i < 4; ++i)
    #pragma unroll
    for (int j = 0; j < 4; ++j) acc[i][j] = z4;

  const int arow = tid >> 3;                       // 0..31
  const int acol = (((tid & 7) ^ (arow & 7)) * 8); // swizzled GLOBAL col chunk
  const u16* Ab = A + (size_t)(bm * 128) * K;
  const u16* Wb = W + (size_t)(bn * 128) * K;
  u16* AsL = &As[0][0] + tid * 8;
  u16* BsL = &Bs[0][0] + tid * 8;

  for (int kt = 0; kt < K; kt += 64) {
    #pragma unroll
    for (int r = 0; r < 4; ++r) {
      gl2lds16(&Ab[(size_t)(arow + r * 32) * K + kt + acol], AsL + r * 2048);
      gl2lds16(&Wb[(size_t)(arow + r * 32) * K + kt + acol], BsL + r * 2048);
    }
    __syncthreads();
    #pragma unroll
    for (int k32 = 0; k32 < 2; ++k32) {
      const int c = (((k32 * 4 + quad) ^ (lr & 7)) * 8);
      f16x8 aF[4], bF[4];
      #pragma unroll
      for (int i = 0; i < 4; ++i) {
        aF[i] = *(const f16x8*)&As[wm + i * 16 + lr][c];
        bF[i] = *(const f16x8*)&Bs[wn + i * 16 + lr][c];
      }
      #pragma unroll
      for (int i = 0; i < 4; ++i)
        #pragma unroll
        for (int j = 0; j < 4; ++j)
          acc[i][j] = __builtin_amdgcn_mfma_f32_16x16x32_f16(aF[i], bF[j], acc[i][j], 0, 0, 0);
    }
    __syncthreads();
  }

  #pragma unroll
  for (int i = 0; i < 4; ++i) {
    int rowb = bm * 128 + wm + i * 16 + quad * 4;
    #pragma unroll
    for (int j = 0; j < 4; ++j) {
      int col = bn * 128 + wn + j * 16 + lr;
      float bv = bias[col];
      #pragma unroll
      for (int r = 0; r < 4; ++r) {
        float v = acc[i][j][r] + bv;
        if (OUTF) ((float*)Cout)[(size_t)(rowb + r) * N + col] = v;
        else      ((u16*)Cout)[(size_t)(rowb + r) * N + col] = f2h(v);
      }
    }
  }
}

// ---------------- fp16 MFMA GEMM 256x256, BK=64, 8 waves, 2-phase counted-vmcnt schedule ----
// (R7 structure, verified: barriers 8->2/tile, bF reused across phases, vmcnt(2) ledger)
__global__ __launch_bounds__(512, 2)
void gemm256_kernel(const u16* __restrict__ A, const u16* __restrict__ W,
                    const float* __restrict__ bias, u16* __restrict__ Cout,
                    int N, int K) {
  __shared__ u16 As[2][256][64];   // 64 KiB
  __shared__ u16 Bs[2][256][64];   // 64 KiB
  const int tid  = threadIdx.x;
  const int flat = blockIdx.x + gridDim.x * blockIdx.y;   // bn-fastest dispatch order
  const int cpx  = (gridDim.x * gridDim.y) >> 3;          // blocks per XCD (30)
  const int nid  = (flat & 7) * cpx + (flat >> 3);
  const int bm   = nid / gridDim.x, bn = nid % gridDim.x;
  const int lane = tid & 63;
  const int wid  = tid >> 6;       // 0..7
  const int wm   = wid >> 2;       // 0..1 (M half within wave grid)
  const int wn   = wid & 3;        // 0..3
  const int lr   = lane & 15, quad = lane >> 4;
  const int NT   = K >> 6;         // K-tiles of 64

  const u16* Ab = A + (size_t)(bm * 256) * K;
  const u16* Wb = W + (size_t)(bn * 256) * K;

  // staging lane geometry: one gl2lds round = 64 rows x 64 cols (512 lanes x 16B)
  const int srr  = tid >> 3;                        // 0..63
  const int scol = ((tid & 7) ^ (srr & 7)) << 3;    // pre-swizzled global col chunk
  const u16* ApL = Ab + (size_t)srr * K + scol;
  const u16* WpL = Wb + (size_t)srr * K + scol;

  auto stA = [&](int b, int row0, int t) {
    gl2lds16(ApL + (size_t)row0 * K + t * 64,        &As[b][row0][0]      + tid * 8);
    gl2lds16(ApL + (size_t)(row0 + 64) * K + t * 64, &As[b][row0 + 64][0] + tid * 8);
  };
  auto stB = [&](int b, int row0, int t) {
    gl2lds16(WpL + (size_t)row0 * K + t * 64,        &Bs[b][row0][0]      + tid * 8);
    gl2lds16(WpL + (size_t)(row0 + 64) * K + t * 64, &Bs[b][row0 + 64][0] + tid * 8);
  };

  f32x4 acc[8][4];
  const f32x4 z4 = {0.f, 0.f, 0.f, 0.f};
  #pragma unroll
  for (int i = 0; i < 8; ++i)
    #pragma unroll
    for (int j = 0; j < 4; ++j) acc[i][j] = z4;

  // fragment column offsets for k32 = 0,1 (swizzled chunk layout)
  const int c0 = (((0 * 4 + quad) ^ (lr & 7)) << 3);
  const int c1 = (((1 * 4 + quad) ^ (lr & 7)) << 3);

  // prologue: tile0 full (8 loads) + tile1 A0 (2 loads); wait tile0, keep tile1-A0 in flight
  stA(0, 0, 0); stA(0, 128, 0);
  stB(0, 0, 0); stB(0, 128, 0);
  stA(1, 0, 1);
  asm volatile("s_waitcnt vmcnt(2)" ::: "memory");
  __builtin_amdgcn_s_barrier();
  __builtin_amdgcn_sched_barrier(0);

  for (int t = 0; t < NT; ++t) {
    const int buf = t & 1, nb = buf ^ 1;

    // ---------- phase A (mq = 0) ----------
    f16x8 bF[2][4], aF0[2][4];
    #pragma unroll
    for (int j = 0; j < 4; ++j) {
      bF[0][j] = *(const f16x8*)&Bs[buf][wn * 64 + j * 16 + lr][c0];
      bF[1][j] = *(const f16x8*)&Bs[buf][wn * 64 + j * 16 + lr][c1];
    }
    #pragma unroll
    for (int i = 0; i < 4; ++i) {
      aF0[0][i] = *(const f16x8*)&As[buf][wm * 64 + i * 16 + lr][c0];
      aF0[1][i] = *(const f16x8*)&As[buf][wm * 64 + i * 16 + lr][c1];
    }
    __builtin_amdgcn_sched_barrier(0);
    if (t + 1 < NT) { stB(nb, 0, t + 1); stB(nb, 128, t + 1); stA(nb, 128, t + 1); }
    __builtin_amdgcn_sched_barrier(0);
    __builtin_amdgcn_s_setprio(1);
    #pragma unroll
    for (int k32 = 0; k32 < 2; ++k32)
      #pragma unroll
      for (int i = 0; i < 4; ++i)
        #pragma unroll
        for (int j = 0; j < 4; ++j)
          acc[i][j] = __builtin_amdgcn_mfma_f32_16x16x32_f16(aF0[k32][i], bF[k32][j], acc[i][j], 0, 0, 0);
    __builtin_amdgcn_s_setprio(0);
    __builtin_amdgcn_sched_barrier(0);
    __builtin_amdgcn_s_barrier();

    // ---------- phase B (mq = 1) ----------
    f16x8 aF1[2][4];
    #pragma unroll
    for (int i = 0; i < 4; ++i) {
      aF1[0][i] = *(const f16x8*)&As[buf][128 + wm * 64 + i * 16 + lr][c0];
      aF1[1][i] = *(const f16x8*)&As[buf][128 + wm * 64 + i * 16 + lr][c1];
    }
    __builtin_amdgcn_sched_barrier(0);
    if (t + 2 < NT) stA(buf, 0, t + 2);
    __builtin_amdgcn_sched_barrier(0);
    __builtin_amdgcn_s_setprio(1);
    #pragma unroll
    for (int k32 = 0; k32 < 2; ++k32)
      #pragma unroll
      for (int i = 0; i < 4; ++i)
        #pragma unroll
        for (int j = 0; j < 4; ++j)
          acc[4 + i][j] = __builtin_amdgcn_mfma_f32_16x16x32_f16(aF1[k32][i], bF[k32][j], acc[4 + i][j], 0, 0, 0);
    __builtin_amdgcn_s_setprio(0);
    if (t < NT - 2) asm volatile("s_waitcnt vmcnt(2)" ::: "memory");
    else            asm volatile("s_waitcnt vmcnt(0)" ::: "memory");
    __builtin_amdgcn_s_barrier();
    __builtin_amdgcn_sched_barrier(0);
  }

  // epilogue: bias add, fp16 store
  #pragma unroll
  for (int mq = 0; mq < 2; ++mq) {
    #pragma unroll
    for (int i = 0; i < 4; ++i) {
      const int rowb = bm * 256 + mq * 128 + wm * 64 + i * 16 + quad * 4;
      #pragma unroll
      for (int j = 0; j < 4; ++j) {
        const int col = bn * 256 + wn * 64 + j * 16 + lr;
        const float bv = bias[col];
        #pragma unroll
        for (int r = 0; r < 4; ++r)
          Cout[(size_t)(rowb + r) * N + col] = f2h(acc[mq * 4 + i][j][r] + bv);
      }
    }
  }
}

// ---------------- RoPE + layout reorg (fully vectorized IO via LDS) ----------------
// block = (64 s-rows, 1 head). qkv[s][3840] -> Qp[h][s][96] (*QSCALE), Kp[h][s][96], Vt[h][d][s]
__global__ __launch_bounds__(256)
void rope_reorg_kernel(const u16* __restrict__ qkv, const float* __restrict__ cosp,
                       const float* __restrict__ sinp, u16* __restrict__ Qp,
                       u16* __restrict__ Kp, u16* __restrict__ Vt) {
  __shared__ u16 Qs[64][80];
  __shared__ u16 Ks[64][80];
  __shared__ u16 Vs[64][88];   // stride 88: rows 16B aligned; col reads conflict-light
  const int tid = threadIdx.x;
  const int s0 = blockIdx.x * 64;
  const int h  = blockIdx.y;

  // load: 64 rows x 80 u16 x 3 arrays, uint4 vectorized
  for (int t = tid; t < 640; t += 256) {
    int r = t / 10, c = (t % 10) * 8;
    size_t g = (size_t)(s0 + r) * O3 + h * HD + c;
    *(uint4*)&Qs[r][c] = *(const uint4*)&qkv[g];
    *(uint4*)&Ks[r][c] = *(const uint4*)&qkv[g + EMB];
    *(uint4*)&Vs[r][c] = *(const uint4*)&qkv[g + 2 * EMB];
  }
  __syncthreads();

  // phase A: rope, 4 outputs per slot, uint2 writes
  for (int t = tid; t < 64 * 24; t += 256) {
    int r = t / 24, d4 = (t % 24) * 4;
    int s = s0 + r;
    size_t po = ((size_t)h * SEQ + s) * HDP + d4;
    if (d4 >= HD) {
      uint2 z = make_uint2(0, 0);
      *(uint2*)&Qp[po] = z; *(uint2*)&Kp[po] = z;
      continue;
    }
    float4 cv = *(const float4*)&cosp[(size_t)s * HD + d4];
    float4 sv = *(const float4*)&sinp[(size_t)s * HD + d4];
    int dp4 = (d4 < 40) ? d4 + 40 : d4 - 40;
    float sgn = (d4 < 40) ? -1.f : 1.f;
    union { u16 h[4]; uint2 v; } oq, ok;
    const float* cp = (const float*)&cv;
    const float* sp = (const float*)&sv;
    #pragma unroll
    for (int j = 0; j < 4; ++j) {
      float q  = h2f(Qs[r][d4 + j]),  k  = h2f(Ks[r][d4 + j]);
      float qp = h2f(Qs[r][dp4 + j]), kp = h2f(Ks[r][dp4 + j]);
      oq.h[j] = f2h((q * cp[j] + sgn * qp * sp[j]) * QSCALE);
      ok.h[j] = f2h(k * cp[j] + sgn * kp * sp[j]);
    }
    *(uint2*)&Qp[po] = oq.v;
    *(uint2*)&Kp[po] = ok.v;
  }

  // phase B: V transpose, uint4 writes along s
  for (int t = tid; t < HD * 8; t += 256) {
    int d = t / 8, sc = (t % 8) * 8;
    union { u16 h[8]; uint4 v; } o;
    #pragma unroll
    for (int j = 0; j < 8; ++j) o.h[j] = Vs[sc + j][d];
    *(uint4*)&Vt[((size_t)(h * HD + d)) * SEQ + s0 + sc] = o.v;
  }
}

// ---------------- flash attention: 4 waves x 32 q, shared K/V reads, T15 ping-pong ----------
// 256 threads, 128 q/block, 512 blocks (grid unchanged). Each wave owns TWO 16-q halves;
// every kF/vF LDS read feeds 2 MFMAs (one per half) -> per-q LDS traffic HALVED (R8 diagnosis:
// LDS datapath ~70% busy was the binding resource). Two independent softmax chains per wave
// double intra-wave ILP, compensating 2-waves/SIMD occupancy.
// K_l [3][64][96] chunk-swizzled; V_l [3][96][64] XOR-swizzled, rows 80..95 ones/zero for
// the MFMA row-sum. Staging: 6 gl2lds/thread/tile (1536 slots / 256 thr); counted vmcnt(6).
__global__ __launch_bounds__(256)
void attn_kernel(const u16* __restrict__ Qp, const u16* __restrict__ Kp,
                 const u16* __restrict__ Vt, u16* __restrict__ attnO) {
  __shared__ u16 K_l[3][64][96];   // 3 x 12 KiB
  __shared__ u16 V_l[3][96][64];   // 3 x 12 KiB
  const int BUFSZ = 6144;          // u16 per buffer (same for K and V)
  const int NT = SEGLEN / 64;      // 16

  const int tid = threadIdx.x;     // 0..255
  const int lane = tid & 63, w = tid >> 6;   // w 0..3
  const int lr = lane & 15, quad = lane >> 4;
  // XCD-chunked remap: flat = bx + 8*by + 128*bz (dispatch order); nid groups 8 blocks
  // of one (h,seg) pair onto one XCD.
  const int flat = blockIdx.x + 8 * blockIdx.y + 128 * blockIdx.z;
  const int nid  = (flat & 7) * 64 + (flat >> 3);
  const int qb   = nid & 7;
  const int h    = (nid >> 3) & 15;
  const int sg   = nid >> 7;
  const int seg0 = sg * SEGLEN;
  const int q0b = seg0 + qb * 128;

  // Q B-fragments, two 16-q halves per wave (q already scaled at rope time)
  f16x8 qF[2][3];
  #pragma unroll
  for (int qh = 0; qh < 2; ++qh) {
    int qrow = q0b + w * 32 + qh * 16 + lr;
    #pragma unroll
    for (int kc = 0; kc < 3; ++kc)
      qF[qh][kc] = *(const f16x8*)&Qp[((size_t)h * SEQ + qrow) * HDP + kc * 32 + quad * 8];
  }
  // force-retire qF loads before the pipelined loop
  asm volatile("" :: "v"(qF[0][0]), "v"(qF[0][1]), "v"(qF[0][2]),
                     "v"(qF[1][0]), "v"(qF[1][1]), "v"(qF[1][2]));
  asm volatile("s_waitcnt vmcnt(0)" ::: "memory");

  // ones/zero pad rows 80..95 of each V buffer (row 80 = 1.0h). 4 u16/thread/buffer.
  {
    u16 val = (tid < 16) ? (u16)0x3C00 : (u16)0;
    #pragma unroll
    for (int b = 0; b < 3; ++b) {
      u16* q = &V_l[0][0][0] + b * BUFSZ + 80 * 64 + tid * 4;
      q[0] = val; q[1] = val; q[2] = val; q[3] = val;
    }
  }

  // staging slot map: 6 rounds x 256 threads = 1536 slots/tile.
  //   s <  768 : K slot s   (r=s/12, c=s%12, chunk-swizzled source)
  //   s < 1408 : V slot s-768 (rv=sv/8, cv=sv%8, XOR-swizzled source)
  //   s >=1408 : duplicate of V slot s-1408 (uniform count filler; same data, same dest)
  const u16* Kbase = Kp + ((size_t)h * SEQ + seg0) * HDP;
  const u16* Vbase = Vt + (size_t)h * HD * SEQ + seg0;
  const u16* pG[6]; u16* dB[6]; int gAdv[6];
  #pragma unroll
  for (int t = 0; t < 6; ++t) {
    int s = t * 256 + tid;
    if (s < 768) {
      int r = s / 12, c = s % 12;
      int ck = (c & ~3) | ((c & 3) ^ ((r >> 1) & 3));  // K chunk swizzle (bank-spread)
      pG[t] = Kbase + (size_t)r * HDP + ck * 8;
      dB[t] = &K_l[0][0][0] + s * 8;
      gAdv[t] = 64 * HDP;
    } else {
      int sv = (s < 1408) ? s - 768 : s - 1408;
      int rv = sv / 8, cv = sv % 8;
      int cg = cv ^ (rv & 7);                          // V XOR chunk swizzle
      pG[t] = Vbase + (size_t)rv * SEQ + cg * 8;
      dB[t] = &V_l[0][0][0] + sv * 8;
      gAdv[t] = 64;
    }
  }

  auto stage_adv = [&](int b) {
    #pragma unroll
    for (int t = 0; t < 6; ++t) {
      gl2lds16(pG[t], dB[t] + b * BUFSZ);
      pG[t] += gAdv[t];
    }
  };

  const f32x4 z4 = {0.f, 0.f, 0.f, 0.f};
  float m_r0 = -3.0e38f, m_r1 = -3.0e38f;
  f32x4 Oacc0[6], Oacc1[6];   // [0..4] = output cols, [5] = MFMA row-sum (ones col of V)
  #pragma unroll
  for (int n = 0; n < 6; ++n) { Oacc0[n] = z4; Oacc1[n] = z4; }

  const int kswz = (lr >> 1) & 3;  // == ((ct*16+lr)>>1)&3 for all ct

  // S^T = K Q^T for one tile, BOTH q-halves: one kF read feeds 2 MFMAs
  auto qk = [&](f32x4 (&S)[2][4], const u16* kb) {
    __builtin_amdgcn_s_setprio(1);
    #pragma unroll
    for (int ct = 0; ct < 4; ++ct) {
      S[0][ct] = z4; S[1][ct] = z4;
      #pragma unroll
      for (int kc = 0; kc < 3; ++kc) {
        f16x8 kF = *(const f16x8*)&kb[(ct * 16 + lr) * 96 + kc * 32 + ((quad ^ kswz) << 3)];
        S[0][ct] = __builtin_amdgcn_mfma_f32_16x16x32_f16(kF, qF[0][kc], S[0][ct], 0, 0, 0);
        S[1][ct] = __builtin_amdgcn_mfma_f32_16x16x32_f16(kF, qF[1][kc], S[1][ct], 0, 0, 0);
      }
    }
    __builtin_amdgcn_s_setprio(0);
  };

  // online softmax (exp2 domain) for one 16-q half -> P fragments
  auto smhalf = [&](f32x4 (&S)[4], f32x4 (&O)[6], float& m_r, f16x4 (&pF)[4]) {
    float mx = fmaxf(fmaxf(S[0].x, S[0].y), fmaxf(S[0].z, S[0].w));
    #pragma unroll
    for (int ct = 1; ct < 4; ++ct)
      mx = fmaxf(mx, fmaxf(fmaxf(S[ct].x, S[ct].y), fmaxf(S[ct].z, S[ct].w)));
    mx = fmaxf(mx, __shfl_xor(mx, 16, 64));
    mx = fmaxf(mx, __shfl_xor(mx, 32, 64));
    float mnew = fmaxf(m_r, mx);
    float alpha = ex2(m_r - mnew);
    m_r = mnew;

    f32x4 mv = {mnew, mnew, mnew, mnew};
    #pragma unroll
    for (int ct = 0; ct < 4; ++ct) S[ct] = exp2_4(S[ct] - mv);

    if (__ballot(alpha != 1.0f)) {
      f32x4 al;
      al.x = __shfl(alpha, quad * 4 + 0, 64);
      al.y = __shfl(alpha, quad * 4 + 1, 64);
      al.z = __shfl(alpha, quad * 4 + 2, 64);
      al.w = __shfl(alpha, quad * 4 + 3, 64);
      #pragma unroll
      for (int n = 0; n < 6; ++n) O[n] *= al;
    }

    #pragma unroll
    for (int ct = 0; ct < 4; ++ct) pF[ct] = pk4(S[ct]);
  };

  // softmax both halves + PV (one vF read feeds 2 MFMAs); row-sum via ones-row acc
  auto smpv = [&](f32x4 (&S)[2][4], const u16* vb) {
    f16x4 pF0[4], pF1[4];
    smhalf(S[0], Oacc0, m_r0, pF0);
    smhalf(S[1], Oacc1, m_r1, pF1);

    __builtin_amdgcn_s_setprio(1);
    #pragma unroll
    for (int ct = 0; ct < 4; ++ct) {
      const int cchunk = 2 * ct + (quad >> 1);
      #pragma unroll
      for (int n = 0; n < 6; ++n) {
        int vrow = n * 16 + lr;
        const u16* vp = vb + vrow * 64 + ((cchunk ^ (vrow & 7)) << 3) + ((quad & 1) << 2);
        f16x4 vF = *(const f16x4*)vp;
        Oacc0[n] = __builtin_amdgcn_mfma_f32_16x16x16f16(pF0[ct], vF, Oacc0[n], 0, 0, 0);
        Oacc1[n] = __builtin_amdgcn_mfma_f32_16x16x16f16(pF1[ct], vF, Oacc1[n], 0, 0, 0);
      }
    }
    __builtin_amdgcn_s_setprio(0);
  };

  // prologue: stage tiles 0,1; force tile 0 resident (tile 1's 6 loads may fly); QK(0)
  stage_adv(0);
  stage_adv(1);
  asm volatile("s_waitcnt vmcnt(6) lgkmcnt(0)" ::: "memory");
  __builtin_amdgcn_s_barrier();
  __builtin_amdgcn_sched_barrier(0);

  f32x4 Sa[2][4], Sb[2][4];
  qk(Sa, &K_l[0][0][0]);    // tile 0 scores

  int buf = 0, sb = 2;
  auto iter = [&](int t, f32x4 (&Scur)[2][4], f32x4 (&Snext)[2][4]) {
    if (t + 2 < NT) {
      stage_adv(sb);                                     // tile t+2 (6 newest loads)
      asm volatile("s_waitcnt vmcnt(6)" ::: "memory");   // force tile t+1 (own wave)
    } else {
      asm volatile("s_waitcnt vmcnt(0)" ::: "memory");   // tail: drain all
    }
    __builtin_amdgcn_s_barrier();                        // tile t+1 resident cross-wave
    const int nbuf = (buf == 2) ? 0 : buf + 1;
    if (t + 1 < NT) qk(Snext, &K_l[0][0][0] + nbuf * BUFSZ);  // MFMA pipe: tile t+1
    smpv(Scur, &V_l[0][0][0] + buf * BUFSZ);                  // VALU+MFMA: tile t
    __builtin_amdgcn_sched_barrier(0);
    __builtin_amdgcn_s_barrier();                        // buffer-reuse guard
    buf = nbuf;
    sb = (sb == 2) ? 0 : sb + 1;
  };
  for (int tt = 0; tt < NT; tt += 2) {
    iter(tt, Sa, Sb);
    iter(tt + 1, Sb, Sa);
  }

  // epilogue: l for q-row quad*4+r sits in lane (quad,0)'s O[5][r] (col 0 = d-row 80)
  auto epi = [&](f32x4 (&O)[6], int qh) {
    f32x4 linv;
    linv.x = 1.0f / __shfl(O[5].x, quad << 4, 64);
    linv.y = 1.0f / __shfl(O[5].y, quad << 4, 64);
    linv.z = 1.0f / __shfl(O[5].z, quad << 4, 64);
    linv.w = 1.0f / __shfl(O[5].w, quad << 4, 64);
    #pragma unroll
    for (int n = 0; n < 5; ++n) {
      int rowb = q0b + w * 32 + qh * 16 + quad * 4;
      int col = h * HD + n * 16 + lr;
      attnO[(size_t)(rowb + 0) * EMB + col] = f2h(O[n].x * linv.x);
      attnO[(size_t)(rowb + 1) * EMB + col] = f2h(O[n].y * linv.y);
      attnO[(size_t)(rowb + 2) * EMB + col] = f2h(O[n].z * linv.z);
      attnO[(size_t)(rowb + 3) * EMB + col] = f2h(O[n].w * linv.w);
    }
  };
  epi(Oacc0, 0);
  epi(Oacc1, 1);
}

extern "C" void kernel_launch(void* const* d_in, const int* in_sizes, int n_in,
                              void* d_out, int out_size, void* d_ws, size_t ws_size,
                              hipStream_t stream) {
  const float* hs     = (const float*)d_in[0];
  const float* w_qkv  = (const float*)d_in[1];
  const float* b_qkv  = (const float*)d_in[2];
  const float* w_proj = (const float*)d_in[3];
  const float* b_proj = (const float*)d_in[4];
  const float* cosp   = (const float*)d_in[5];
  const float* sinp   = (const float*)d_in[6];
  float* out = (float*)d_out;

  char* p = (char*)d_ws;
  auto take = [&](size_t bytes) { char* q = p; p += (bytes + 255) & ~(size_t)255; return q; };
  u16* hsH    = (u16*)take((size_t)SEQ * EMB * 2);
  u16* wqkvH  = (u16*)take((size_t)O3 * EMB * 2);
  u16* wprojH = (u16*)take((size_t)EMB * EMB * 2);
  u16* qkvO   = (u16*)take((size_t)SEQ * O3 * 2);
  u16* Qp     = (u16*)take((size_t)NH * SEQ * HDP * 2);
  u16* Kp     = (u16*)take((size_t)NH * SEQ * HDP * 2);
  u16* Vt     = (u16*)take((size_t)NH * HD * SEQ * 2);
  u16* attnH  = (u16*)take((size_t)SEQ * EMB * 2);

  int ncvt = (CVT_N1 + CVT_N2 + CVT_N3) / 256;
  cvt_all_kernel<<<ncvt, 256, 0, stream>>>(hs, w_qkv, w_proj, hsH, wqkvH, wprojH);

  // QKV GEMM: 256^2 tile, 2-phase counted-vmcnt schedule + XCD swizzle. 240 blocks = 1/CU.
  gemm256_kernel<<<dim3(O3 / 256, SEQ / 256), 512, 0, stream>>>(hsH, wqkvH, b_qkv, qkvO, O3, EMB);

  rope_reorg_kernel<<<dim3(SEQ / 64, NH), 256, 0, stream>>>(qkvO, cosp, sinp, Qp, Kp, Vt);

  // attn: 4 waves x 32 q (256 thr), shared K/V reads, triple-buffer + T15 + XCD swizzle.
  attn_kernel<<<dim3(SEGLEN / 128, NH, NSEG), 256, 0, stream>>>(Qp, Kp, Vt, attnH);

  // proj GEMM: 128^2 tile + XCD swizzle (320 blocks, 40/XCD)
  gemm_bias_kernel<1><<<dim3(EMB / 128, SEQ / 128), 256, 0, stream>>>(attnH, wprojH, b_proj, out, EMB, EMB);
}

// Round 10
// 221.195 us; speedup vs baseline: 1.1642x; 1.1642x over previous
//
#include <hip/hip_runtime.h>

#define SEQ   4096
#define EMB   1280
#define NH    16
#define HD    80
#define HDP   96
#define O3    3840
#define SEGLEN 1024
#define NSEG  4
// sqrt(80) * log2(e): scores computed in log2 domain -> softmax uses native v_exp_f32 (exp2)
#define QSCALE (8.94427190999915878564f * 1.44269504088896340736f)

typedef unsigned short u16;
typedef __attribute__((ext_vector_type(8))) _Float16 f16x8;
typedef __attribute__((ext_vector_type(4))) _Float16 f16x4;
typedef __attribute__((ext_vector_type(2))) __fp16   h16x2;
typedef __attribute__((ext_vector_type(4))) float    f32x4;

__device__ __forceinline__ float ex2(float x) { return __builtin_amdgcn_exp2f(x); }

__device__ __forceinline__ u16 f2h(float f) {
  union { _Float16 h; u16 u; } v; v.h = (_Float16)f; return v.u;
}
__device__ __forceinline__ float h2f(u16 b) {
  union { u16 u; _Float16 h; } v; v.u = b; return (float)v.h;
}
__device__ __forceinline__ f32x4 exp2_4(f32x4 x) {
  f32x4 r; r.x = ex2(x.x); r.y = ex2(x.y); r.z = ex2(x.z); r.w = ex2(x.w); return r;
}
__device__ __forceinline__ f16x4 pk4(f32x4 s) {
  union { h16x2 h[2]; f16x4 f; } u;
  u.h[0] = __builtin_amdgcn_cvt_pkrtz(s.x, s.y);
  u.h[1] = __builtin_amdgcn_cvt_pkrtz(s.z, s.w);
  return u.f;
}
// async global->LDS, 16B per lane. LDS dest must be wave-uniform base + lane*16.
__device__ __forceinline__ void gl2lds16(const u16* g, u16* l) {
  __builtin_amdgcn_global_load_lds(
      (const __attribute__((address_space(1))) unsigned int*)g,
      (__attribute__((address_space(3))) unsigned int*)l, 16, 0, 0);
}

// ---------------- fused fp32 -> fp16 convert for hs, w_qkv, w_proj ----------------
#define CVT_N1 (SEQ * EMB / 4)
#define CVT_N2 (O3 * EMB / 4)
#define CVT_N3 (EMB * EMB / 4)
__global__ void cvt_all_kernel(const float* __restrict__ a, const float* __restrict__ b,
                               const float* __restrict__ c, u16* __restrict__ oa,
                               u16* __restrict__ ob, u16* __restrict__ oc) {
  int i = blockIdx.x * blockDim.x + threadIdx.x;
  const float* src; u16* dst; int j = i;
  if (j < CVT_N1)                { src = a; dst = oa; }
  else if (j < CVT_N1 + CVT_N2)  { src = b; dst = ob; j -= CVT_N1; }
  else                           { src = c; dst = oc; j -= CVT_N1 + CVT_N2; }
  float4 f = ((const float4*)src)[j];
  union { u16 h[4]; uint2 v; } o;
  o.h[0] = f2h(f.x); o.h[1] = f2h(f.y); o.h[2] = f2h(f.z); o.h[3] = f2h(f.w);
  ((uint2*)dst)[j] = o.v;
}

// ---------------- proj GEMM 128x128, BK=64, 4 waves, 2-phase counted-vmcnt schedule ----
// Half-scale port of the verified gemm256 R7 schedule. 4 waves each own a 32-wide N-slice
// over all 128 M rows (acc[8][2]). Per tile t (buf=t&1, nb=buf^1):
//  Phase A: ds_read bF[2][2] (both k32, reused) + aF0[2][4] (12 b128); stage B0,B1,A1(t+1)
//           -> nb (6 gl2lds); 16 MFMA; s_barrier (As[buf][0:64) reads retired)
//  Phase B: ds_read aF1[2][4] (8); stage A0(t+2) -> As[buf][0:64) (2); 16 MFMA;
//           s_waitcnt vmcnt(2) (tail 0); s_barrier
// Ledger identical to gemm256: at t.B's wait only t.B's own 2 loads are younger than
// tile t+1's staging set -> vmcnt(2) forces t+1 resident.
// XCD-chunked swizzle: 320 blocks -> 40/XCD.
__global__ __launch_bounds__(256, 2)
void gemm128_kernel(const u16* __restrict__ A, const u16* __restrict__ W,
                    const float* __restrict__ bias, float* __restrict__ Cout,
                    int N, int K) {
  __shared__ u16 As[2][128][64];   // 32 KiB
  __shared__ u16 Bs[2][128][64];   // 32 KiB
  const int tid  = threadIdx.x;
  const int flat = blockIdx.x + gridDim.x * blockIdx.y;
  const int cpx  = (gridDim.x * gridDim.y) >> 3;
  const int nid  = (flat & 7) * cpx + (flat >> 3);
  const int bm   = nid / gridDim.x, bn = nid % gridDim.x;
  const int lane = tid & 63;
  const int wid  = tid >> 6;       // 0..3 (N-slice of 32)
  const int lr   = lane & 15, quad = lane >> 4;
  const int NT   = K >> 6;

  const u16* Ab = A + (size_t)(bm * 128) * K;
  const u16* Wb = W + (size_t)(bn * 128) * K;

  // staging lane geometry: one gl2lds round = 32 rows x 64 cols (256 lanes x 16B)
  const int arow = tid >> 3;                        // 0..31
  const int acol = ((tid & 7) ^ (arow & 7)) << 3;   // pre-swizzled global col chunk
  const u16* ApL = Ab + (size_t)arow * K + acol;
  const u16* WpL = Wb + (size_t)arow * K + acol;

  auto stA = [&](int b, int row0, int t) {
    gl2lds16(ApL + (size_t)row0 * K + t * 64,        &As[b][row0][0]      + tid * 8);
    gl2lds16(ApL + (size_t)(row0 + 32) * K + t * 64, &As[b][row0 + 32][0] + tid * 8);
  };
  auto stB = [&](int b, int row0, int t) {
    gl2lds16(WpL + (size_t)row0 * K + t * 64,        &Bs[b][row0][0]      + tid * 8);
    gl2lds16(WpL + (size_t)(row0 + 32) * K + t * 64, &Bs[b][row0 + 32][0] + tid * 8);
  };

  f32x4 acc[8][2];
  const f32x4 z4 = {0.f, 0.f, 0.f, 0.f};
  #pragma unroll
  for (int i = 0; i < 8; ++i) { acc[i][0] = z4; acc[i][1] = z4; }

  const int c0 = (((0 * 4 + quad) ^ (lr & 7)) << 3);
  const int c1 = (((1 * 4 + quad) ^ (lr & 7)) << 3);

  // prologue: tile0 full (8 loads) + tile1 A0 (2); wait tile0, keep tile1-A0 in flight
  stA(0, 0, 0); stA(0, 64, 0);
  stB(0, 0, 0); stB(0, 64, 0);
  stA(1, 0, 1);
  asm volatile("s_waitcnt vmcnt(2)" ::: "memory");
  __builtin_amdgcn_s_barrier();
  __builtin_amdgcn_sched_barrier(0);

  for (int t = 0; t < NT; ++t) {
    const int buf = t & 1, nb = buf ^ 1;

    // ---------- phase A (M rows 0:64) ----------
    f16x8 bF[2][2], aF0[2][4];
    #pragma unroll
    for (int j = 0; j < 2; ++j) {
      bF[0][j] = *(const f16x8*)&Bs[buf][wid * 32 + j * 16 + lr][c0];
      bF[1][j] = *(const f16x8*)&Bs[buf][wid * 32 + j * 16 + lr][c1];
    }
    #pragma unroll
    for (int i = 0; i < 4; ++i) {
      aF0[0][i] = *(const f16x8*)&As[buf][i * 16 + lr][c0];
      aF0[1][i] = *(const f16x8*)&As[buf][i * 16 + lr][c1];
    }
    __builtin_amdgcn_sched_barrier(0);
    if (t + 1 < NT) { stB(nb, 0, t + 1); stB(nb, 64, t + 1); stA(nb, 64, t + 1); }
    __builtin_amdgcn_sched_barrier(0);
    __builtin_amdgcn_s_setprio(1);
    #pragma unroll
    for (int k32 = 0; k32 < 2; ++k32)
      #pragma unroll
      for (int i = 0; i < 4; ++i)
        #pragma unroll
        for (int j = 0; j < 2; ++j)
          acc[i][j] = __builtin_amdgcn_mfma_f32_16x16x32_f16(aF0[k32][i], bF[k32][j], acc[i][j], 0, 0, 0);
    __builtin_amdgcn_s_setprio(0);
    __builtin_amdgcn_sched_barrier(0);
    __builtin_amdgcn_s_barrier();   // As[buf][0:64) reads retired -> phase B may overwrite

    // ---------- phase B (M rows 64:128) ----------
    f16x8 aF1[2][4];
    #pragma unroll
    for (int i = 0; i < 4; ++i) {
      aF1[0][i] = *(const f16x8*)&As[buf][64 + i * 16 + lr][c0];
      aF1[1][i] = *(const f16x8*)&As[buf][64 + i * 16 + lr][c1];
    }
    __builtin_amdgcn_sched_barrier(0);
    if (t + 2 < NT) stA(buf, 0, t + 2);
    __builtin_amdgcn_sched_barrier(0);
    __builtin_amdgcn_s_setprio(1);
    #pragma unroll
    for (int k32 = 0; k32 < 2; ++k32)
      #pragma unroll
      for (int i = 0; i < 4; ++i)
        #pragma unroll
        for (int j = 0; j < 2; ++j)
          acc[4 + i][j] = __builtin_amdgcn_mfma_f32_16x16x32_f16(aF1[k32][i], bF[k32][j], acc[4 + i][j], 0, 0, 0);
    __builtin_amdgcn_s_setprio(0);
    if (t < NT - 2) asm volatile("s_waitcnt vmcnt(2)" ::: "memory");
    else            asm volatile("s_waitcnt vmcnt(0)" ::: "memory");
    __builtin_amdgcn_s_barrier();
    __builtin_amdgcn_sched_barrier(0);
  }

  // epilogue: bias add, fp32 store
  #pragma unroll
  for (int mq = 0; mq < 2; ++mq) {
    #pragma unroll
    for (int i = 0; i < 4; ++i) {
      const int rowb = bm * 128 + mq * 64 + i * 16 + quad * 4;
      #pragma unroll
      for (int j = 0; j < 2; ++j) {
        const int col = bn * 128 + wid * 32 + j * 16 + lr;
        const float bv = bias[col];
        #pragma unroll
        for (int r = 0; r < 4; ++r)
          Cout[(size_t)(rowb + r) * N + col] = acc[mq * 4 + i][j][r] + bv;
      }
    }
  }
}

// ---------------- fp16 MFMA GEMM 256x256, BK=64, 8 waves, 2-phase counted-vmcnt schedule ----
// (R7 structure, verified: barriers 8->2/tile, bF reused across phases, vmcnt(2) ledger)
__global__ __launch_bounds__(512, 2)
void gemm256_kernel(const u16* __restrict__ A, const u16* __restrict__ W,
                    const float* __restrict__ bias, u16* __restrict__ Cout,
                    int N, int K) {
  __shared__ u16 As[2][256][64];   // 64 KiB
  __shared__ u16 Bs[2][256][64];   // 64 KiB
  const int tid  = threadIdx.x;
  const int flat = blockIdx.x + gridDim.x * blockIdx.y;   // bn-fastest dispatch order
  const int cpx  = (gridDim.x * gridDim.y) >> 3;          // blocks per XCD (30)
  const int nid  = (flat & 7) * cpx + (flat >> 3);
  const int bm   = nid / gridDim.x, bn = nid % gridDim.x;
  const int lane = tid & 63;
  const int wid  = tid >> 6;       // 0..7
  const int wm   = wid >> 2;       // 0..1 (M half within wave grid)
  const int wn   = wid & 3;        // 0..3
  const int lr   = lane & 15, quad = lane >> 4;
  const int NT   = K >> 6;         // K-tiles of 64

  const u16* Ab = A + (size_t)(bm * 256) * K;
  const u16* Wb = W + (size_t)(bn * 256) * K;

  // staging lane geometry: one gl2lds round = 64 rows x 64 cols (512 lanes x 16B)
  const int srr  = tid >> 3;                        // 0..63
  const int scol = ((tid & 7) ^ (srr & 7)) << 3;    // pre-swizzled global col chunk
  const u16* ApL = Ab + (size_t)srr * K + scol;
  const u16* WpL = Wb + (size_t)srr * K + scol;

  auto stA = [&](int b, int row0, int t) {
    gl2lds16(ApL + (size_t)row0 * K + t * 64,        &As[b][row0][0]      + tid * 8);
    gl2lds16(ApL + (size_t)(row0 + 64) * K + t * 64, &As[b][row0 + 64][0] + tid * 8);
  };
  auto stB = [&](int b, int row0, int t) {
    gl2lds16(WpL + (size_t)row0 * K + t * 64,        &Bs[b][row0][0]      + tid * 8);
    gl2lds16(WpL + (size_t)(row0 + 64) * K + t * 64, &Bs[b][row0 + 64][0] + tid * 8);
  };

  f32x4 acc[8][4];
  const f32x4 z4 = {0.f, 0.f, 0.f, 0.f};
  #pragma unroll
  for (int i = 0; i < 8; ++i)
    #pragma unroll
    for (int j = 0; j < 4; ++j) acc[i][j] = z4;

  // fragment column offsets for k32 = 0,1 (swizzled chunk layout)
  const int c0 = (((0 * 4 + quad) ^ (lr & 7)) << 3);
  const int c1 = (((1 * 4 + quad) ^ (lr & 7)) << 3);

  // prologue: tile0 full (8 loads) + tile1 A0 (2 loads); wait tile0, keep tile1-A0 in flight
  stA(0, 0, 0); stA(0, 128, 0);
  stB(0, 0, 0); stB(0, 128, 0);
  stA(1, 0, 1);
  asm volatile("s_waitcnt vmcnt(2)" ::: "memory");
  __builtin_amdgcn_s_barrier();
  __builtin_amdgcn_sched_barrier(0);

  for (int t = 0; t < NT; ++t) {
    const int buf = t & 1, nb = buf ^ 1;

    // ---------- phase A (mq = 0) ----------
    f16x8 bF[2][4], aF0[2][4];
    #pragma unroll
    for (int j = 0; j < 4; ++j) {
      bF[0][j] = *(const f16x8*)&Bs[buf][wn * 64 + j * 16 + lr][c0];
      bF[1][j] = *(const f16x8*)&Bs[buf][wn * 64 + j * 16 + lr][c1];
    }
    #pragma unroll
    for (int i = 0; i < 4; ++i) {
      aF0[0][i] = *(const f16x8*)&As[buf][wm * 64 + i * 16 + lr][c0];
      aF0[1][i] = *(const f16x8*)&As[buf][wm * 64 + i * 16 + lr][c1];
    }
    __builtin_amdgcn_sched_barrier(0);
    if (t + 1 < NT) { stB(nb, 0, t + 1); stB(nb, 128, t + 1); stA(nb, 128, t + 1); }
    __builtin_amdgcn_sched_barrier(0);
    __builtin_amdgcn_s_setprio(1);
    #pragma unroll
    for (int k32 = 0; k32 < 2; ++k32)
      #pragma unroll
      for (int i = 0; i < 4; ++i)
        #pragma unroll
        for (int j = 0; j < 4; ++j)
          acc[i][j] = __builtin_amdgcn_mfma_f32_16x16x32_f16(aF0[k32][i], bF[k32][j], acc[i][j], 0, 0, 0);
    __builtin_amdgcn_s_setprio(0);
    __builtin_amdgcn_sched_barrier(0);
    __builtin_amdgcn_s_barrier();

    // ---------- phase B (mq = 1) ----------
    f16x8 aF1[2][4];
    #pragma unroll
    for (int i = 0; i < 4; ++i) {
      aF1[0][i] = *(const f16x8*)&As[buf][128 + wm * 64 + i * 16 + lr][c0];
      aF1[1][i] = *(const f16x8*)&As[buf][128 + wm * 64 + i * 16 + lr][c1];
    }
    __builtin_amdgcn_sched_barrier(0);
    if (t + 2 < NT) stA(buf, 0, t + 2);
    __builtin_amdgcn_sched_barrier(0);
    __builtin_amdgcn_s_setprio(1);
    #pragma unroll
    for (int k32 = 0; k32 < 2; ++k32)
      #pragma unroll
      for (int i = 0; i < 4; ++i)
        #pragma unroll
        for (int j = 0; j < 4; ++j)
          acc[4 + i][j] = __builtin_amdgcn_mfma_f32_16x16x32_f16(aF1[k32][i], bF[k32][j], acc[4 + i][j], 0, 0, 0);
    __builtin_amdgcn_s_setprio(0);
    if (t < NT - 2) asm volatile("s_waitcnt vmcnt(2)" ::: "memory");
    else            asm volatile("s_waitcnt vmcnt(0)" ::: "memory");
    __builtin_amdgcn_s_barrier();
    __builtin_amdgcn_sched_barrier(0);
  }

  // epilogue: bias add, fp16 store
  #pragma unroll
  for (int mq = 0; mq < 2; ++mq) {
    #pragma unroll
    for (int i = 0; i < 4; ++i) {
      const int rowb = bm * 256 + mq * 128 + wm * 64 + i * 16 + quad * 4;
      #pragma unroll
      for (int j = 0; j < 4; ++j) {
        const int col = bn * 256 + wn * 64 + j * 16 + lr;
        const float bv = bias[col];
        #pragma unroll
        for (int r = 0; r < 4; ++r)
          Cout[(size_t)(rowb + r) * N + col] = f2h(acc[mq * 4 + i][j][r] + bv);
      }
    }
  }
}

// ---------------- RoPE + layout reorg (fully vectorized IO via LDS) ----------------
// block = (64 s-rows, 1 head). qkv[s][3840] -> Qp[h][s][96] (*QSCALE), Kp[h][s][96], Vt[h][d][s]
__global__ __launch_bounds__(256)
void rope_reorg_kernel(const u16* __restrict__ qkv, const float* __restrict__ cosp,
                       const float* __restrict__ sinp, u16* __restrict__ Qp,
                       u16* __restrict__ Kp, u16* __restrict__ Vt) {
  __shared__ u16 Qs[64][80];
  __shared__ u16 Ks[64][80];
  __shared__ u16 Vs[64][88];   // stride 88: rows 16B aligned; col reads conflict-light
  const int tid = threadIdx.x;
  const int s0 = blockIdx.x * 64;
  const int h  = blockIdx.y;

  // load: 64 rows x 80 u16 x 3 arrays, uint4 vectorized
  for (int t = tid; t < 640; t += 256) {
    int r = t / 10, c = (t % 10) * 8;
    size_t g = (size_t)(s0 + r) * O3 + h * HD + c;
    *(uint4*)&Qs[r][c] = *(const uint4*)&qkv[g];
    *(uint4*)&Ks[r][c] = *(const uint4*)&qkv[g + EMB];
    *(uint4*)&Vs[r][c] = *(const uint4*)&qkv[g + 2 * EMB];
  }
  __syncthreads();

  // phase A: rope, 4 outputs per slot, uint2 writes
  for (int t = tid; t < 64 * 24; t += 256) {
    int r = t / 24, d4 = (t % 24) * 4;
    int s = s0 + r;
    size_t po = ((size_t)h * SEQ + s) * HDP + d4;
    if (d4 >= HD) {
      uint2 z = make_uint2(0, 0);
      *(uint2*)&Qp[po] = z; *(uint2*)&Kp[po] = z;
      continue;
    }
    float4 cv = *(const float4*)&cosp[(size_t)s * HD + d4];
    float4 sv = *(const float4*)&sinp[(size_t)s * HD + d4];
    int dp4 = (d4 < 40) ? d4 + 40 : d4 - 40;
    float sgn = (d4 < 40) ? -1.f : 1.f;
    union { u16 h[4]; uint2 v; } oq, ok;
    const float* cp = (const float*)&cv;
    const float* sp = (const float*)&sv;
    #pragma unroll
    for (int j = 0; j < 4; ++j) {
      float q  = h2f(Qs[r][d4 + j]),  k  = h2f(Ks[r][d4 + j]);
      float qp = h2f(Qs[r][dp4 + j]), kp = h2f(Ks[r][dp4 + j]);
      oq.h[j] = f2h((q * cp[j] + sgn * qp * sp[j]) * QSCALE);
      ok.h[j] = f2h(k * cp[j] + sgn * kp * sp[j]);
    }
    *(uint2*)&Qp[po] = oq.v;
    *(uint2*)&Kp[po] = ok.v;
  }

  // phase B: V transpose, uint4 writes along s
  for (int t = tid; t < HD * 8; t += 256) {
    int d = t / 8, sc = (t % 8) * 8;
    union { u16 h[8]; uint4 v; } o;
    #pragma unroll
    for (int j = 0; j < 8; ++j) o.h[j] = Vs[sc + j][d];
    *(uint4*)&Vt[((size_t)(h * HD + d)) * SEQ + s0 + sc] = o.v;
  }
}

// ---------------- flash attention: 128q, triple-buffered, QK(t+1) || softmax+PV(t) ----------
// (R8 version, verified 49.0 us — 8 waves x 16 q, T15 ping-pong, counted vmcnt(3).)
__global__ __launch_bounds__(512)
void attn_kernel(const u16* __restrict__ Qp, const u16* __restrict__ Kp,
                 const u16* __restrict__ Vt, u16* __restrict__ attnO) {
  __shared__ u16 K_l[3][64][96];   // 3 x 12 KiB
  __shared__ u16 V_l[3][96][64];   // 3 x 12 KiB
  const int BUFSZ = 6144;          // u16 per buffer (same for K and V)
  const int NT = SEGLEN / 64;      // 16

  const int tid = threadIdx.x;     // 0..511
  const int lane = tid & 63, w = tid >> 6;   // w 0..7
  const int lr = lane & 15, quad = lane >> 4;
  // XCD-chunked remap: flat = bx + 8*by + 128*bz (dispatch order); nid groups 8 blocks
  // of one (h,seg) pair onto one XCD.
  const int flat = blockIdx.x + 8 * blockIdx.y + 128 * blockIdx.z;
  const int nid  = (flat & 7) * 64 + (flat >> 3);
  const int qb   = nid & 7;
  const int h    = (nid >> 3) & 15;
  const int sg   = nid >> 7;
  const int seg0 = sg * SEGLEN;
  const int q0b = seg0 + qb * 128;

  // Q B-fragments (q already scaled by sqrt(80)*log2e at rope time)
  f16x8 qF[3];
  {
    int qrow = q0b + w * 16 + lr;
    #pragma unroll
    for (int kc = 0; kc < 3; ++kc)
      qF[kc] = *(const f16x8*)&Qp[((size_t)h * SEQ + qrow) * HDP + kc * 32 + quad * 8];
  }
  // force-retire qF loads NOW so the compiler's waitcnt insertion marks them complete
  // before the pipelined loop
  asm volatile("" :: "v"(qF[0]), "v"(qF[1]), "v"(qF[2]));
  asm volatile("s_waitcnt vmcnt(0)" ::: "memory");

  // ones/zero pad rows 80..95 of each V buffer (row 80 = 1.0h). 2 u16/thread/buffer.
  {
    u16 val = (tid < 32) ? (u16)0x3C00 : (u16)0;
    #pragma unroll
    for (int b = 0; b < 3; ++b) {
      u16* q = &V_l[0][0][0] + b * BUFSZ + 80 * 64 + tid * 2;
      q[0] = val; q[1] = val;
    }
  }

  // staging slot map: 3 rounds x 512 threads = 1536 slots/tile.
  const u16* Kbase = Kp + ((size_t)h * SEQ + seg0) * HDP;
  const u16* Vbase = Vt + (size_t)h * HD * SEQ + seg0;
  const u16* pG[3]; u16* dB[3]; int gAdv[3];
  #pragma unroll
  for (int t = 0; t < 3; ++t) {
    int s = t * 512 + tid;
    if (s < 768) {
      int r = s / 12, c = s % 12;
      int ck = (c & ~3) | ((c & 3) ^ ((r >> 1) & 3));  // K chunk swizzle (bank-spread)
      pG[t] = Kbase + (size_t)r * HDP + ck * 8;
      dB[t] = &K_l[0][0][0] + s * 8;
      gAdv[t] = 64 * HDP;
    } else {
      int sv = (s < 1408) ? s - 768 : s - 1408;
      int rv = sv / 8, cv = sv % 8;
      int cg = cv ^ (rv & 7);                          // V XOR chunk swizzle
      pG[t] = Vbase + (size_t)rv * SEQ + cg * 8;
      dB[t] = &V_l[0][0][0] + sv * 8;
      gAdv[t] = 64;
    }
  }

  auto stage_adv = [&](int b) {
    #pragma unroll
    for (int t = 0; t < 3; ++t) {
      gl2lds16(pG[t], dB[t] + b * BUFSZ);
      pG[t] += gAdv[t];
    }
  };

  const f32x4 z4 = {0.f, 0.f, 0.f, 0.f};
  float m_r = -3.0e38f;
  f32x4 Oacc[6];   // [0..4] = output cols, [5] = MFMA row-sum (ones column of V)
  #pragma unroll
  for (int n = 0; n < 6; ++n) Oacc[n] = z4;

  const int kswz = (lr >> 1) & 3;  // == ((ct*16+lr)>>1)&3 for all ct

  // S^T = K Q^T for one tile: lane holds scores for q=lr at c = ct*16+quad*4+r (log2 dom.)
  auto qk = [&](f32x4 (&S)[4], const u16* kb) {
    __builtin_amdgcn_s_setprio(1);
    #pragma unroll
    for (int ct = 0; ct < 4; ++ct) {
      S[ct] = z4;
      #pragma unroll
      for (int kc = 0; kc < 3; ++kc) {
        f16x8 kF = *(const f16x8*)&kb[(ct * 16 + lr) * 96 + kc * 32 + ((quad ^ kswz) << 3)];
        S[ct] = __builtin_amdgcn_mfma_f32_16x16x32_f16(kF, qF[kc], S[ct], 0, 0, 0);
      }
    }
    __builtin_amdgcn_s_setprio(0);
  };

  // online softmax (exp2 domain) + PV for one tile; row-sum l via ones-row MFMA acc
  auto smpv = [&](f32x4 (&S)[4], const u16* vb) {
    float mx = fmaxf(fmaxf(S[0].x, S[0].y), fmaxf(S[0].z, S[0].w));
    #pragma unroll
    for (int ct = 1; ct < 4; ++ct)
      mx = fmaxf(mx, fmaxf(fmaxf(S[ct].x, S[ct].y), fmaxf(S[ct].z, S[ct].w)));
    mx = fmaxf(mx, __shfl_xor(mx, 16, 64));
    mx = fmaxf(mx, __shfl_xor(mx, 32, 64));
    float mnew = fmaxf(m_r, mx);
    float alpha = ex2(m_r - mnew);
    m_r = mnew;

    f32x4 mv = {mnew, mnew, mnew, mnew};
    #pragma unroll
    for (int ct = 0; ct < 4; ++ct) S[ct] = exp2_4(S[ct] - mv);

    // rescale history only when some lane's max moved (wave-uniform skip)
    if (__ballot(alpha != 1.0f)) {
      f32x4 al;
      al.x = __shfl(alpha, quad * 4 + 0, 64);
      al.y = __shfl(alpha, quad * 4 + 1, 64);
      al.z = __shfl(alpha, quad * 4 + 2, 64);
      al.w = __shfl(alpha, quad * 4 + 3, 64);
      #pragma unroll
      for (int n = 0; n < 6; ++n) Oacc[n] *= al;
    }

    f16x4 pF[4];
    #pragma unroll
    for (int ct = 0; ct < 4; ++ct) pF[ct] = pk4(S[ct]);

    __builtin_amdgcn_s_setprio(1);
    #pragma unroll
    for (int ct = 0; ct < 4; ++ct) {
      const int cchunk = 2 * ct + (quad >> 1);
      #pragma unroll
      for (int n = 0; n < 6; ++n) {
        int vrow = n * 16 + lr;
        const u16* vp = vb + vrow * 64 + ((cchunk ^ (vrow & 7)) << 3) + ((quad & 1) << 2);
        f16x4 vF = *(const f16x4*)vp;
        Oacc[n] = __builtin_amdgcn_mfma_f32_16x16x16f16(pF[ct], vF, Oacc[n], 0, 0, 0);
      }
    }
    __builtin_amdgcn_s_setprio(0);
  };

  // prologue: stage tiles 0,1; force tile 0 resident (tile 1's 3 loads may fly); QK(0)
  stage_adv(0);
  stage_adv(1);
  asm volatile("s_waitcnt vmcnt(3) lgkmcnt(0)" ::: "memory");
  __builtin_amdgcn_s_barrier();
  __builtin_amdgcn_sched_barrier(0);

  f32x4 Sa[4], Sb[4];
  qk(Sa, &K_l[0][0][0]);    // tile 0 scores

  int buf = 0, sb = 2;
  auto iter = [&](int t, f32x4 (&Scur)[4], f32x4 (&Snext)[4]) {
    if (t + 2 < NT) {
      stage_adv(sb);                                     // tile t+2 (3 newest loads)
      asm volatile("s_waitcnt vmcnt(3)" ::: "memory");   // force tile t+1 (own wave)
    } else {
      asm volatile("s_waitcnt vmcnt(0)" ::: "memory");   // tail: drain all
    }
    __builtin_amdgcn_s_barrier();                        // tile t+1 resident cross-wave
    const int nbuf = (buf == 2) ? 0 : buf + 1;
    if (t + 1 < NT) qk(Snext, &K_l[0][0][0] + nbuf * BUFSZ);  // MFMA pipe: tile t+1
    smpv(Scur, &V_l[0][0][0] + buf * BUFSZ);                  // VALU+MFMA: tile t
    __builtin_amdgcn_sched_barrier(0);
    __builtin_amdgcn_s_barrier();                        // buffer-reuse guard
    buf = nbuf;
    sb = (sb == 2) ? 0 : sb + 1;
  };
  for (int tt = 0; tt < NT; tt += 2) {
    iter(tt, Sa, Sb);
    iter(tt + 1, Sb, Sa);
  }

  // epilogue: l for q-row quad*4+r sits in lane (quad,0)'s Oacc[5][r] (col 0 = d-row 80)
  f32x4 linv;
  linv.x = 1.0f / __shfl(Oacc[5].x, quad << 4, 64);
  linv.y = 1.0f / __shfl(Oacc[5].y, quad << 4, 64);
  linv.z = 1.0f / __shfl(Oacc[5].z, quad << 4, 64);
  linv.w = 1.0f / __shfl(Oacc[5].w, quad << 4, 64);
  #pragma unroll
  for (int n = 0; n < 5; ++n) {
    int rowb = q0b + w * 16 + quad * 4;
    int col = h * HD + n * 16 + lr;
    attnO[(size_t)(rowb + 0) * EMB + col] = f2h(Oacc[n].x * linv.x);
    attnO[(size_t)(rowb + 1) * EMB + col] = f2h(Oacc[n].y * linv.y);
    attnO[(size_t)(rowb + 2) * EMB + col] = f2h(Oacc[n].z * linv.z);
    attnO[(size_t)(rowb + 3) * EMB + col] = f2h(Oacc[n].w * linv.w);
  }
}

extern "C" void kernel_launch(void* const* d_in, const int* in_sizes, int n_in,
                              void* d_out, int out_size, void* d_ws, size_t ws_size,
                              hipStream_t stream) {
  const float* hs     = (const float*)d_in[0];
  const float* w_qkv  = (const float*)d_in[1];
  const float* b_qkv  = (const float*)d_in[2];
  const float* w_proj = (const float*)d_in[3];
  const float* b_proj = (const float*)d_in[4];
  const float* cosp   = (const float*)d_in[5];
  const float* sinp   = (const float*)d_in[6];
  float* out = (float*)d_out;

  char* p = (char*)d_ws;
  auto take = [&](size_t bytes) { char* q = p; p += (bytes + 255) & ~(size_t)255; return q; };
  u16* hsH    = (u16*)take((size_t)SEQ * EMB * 2);
  u16* wqkvH  = (u16*)take((size_t)O3 * EMB * 2);
  u16* wprojH = (u16*)take((size_t)EMB * EMB * 2);
  u16* qkvO   = (u16*)take((size_t)SEQ * O3 * 2);
  u16* Qp     = (u16*)take((size_t)NH * SEQ * HDP * 2);
  u16* Kp     = (u16*)take((size_t)NH * SEQ * HDP * 2);
  u16* Vt     = (u16*)take((size_t)NH * HD * SEQ * 2);
  u16* attnH  = (u16*)take((size_t)SEQ * EMB * 2);

  int ncvt = (CVT_N1 + CVT_N2 + CVT_N3) / 256;
  cvt_all_kernel<<<ncvt, 256, 0, stream>>>(hs, w_qkv, w_proj, hsH, wqkvH, wprojH);

  // QKV GEMM: 256^2 tile, 2-phase counted-vmcnt schedule + XCD swizzle. 240 blocks = 1/CU.
  gemm256_kernel<<<dim3(O3 / 256, SEQ / 256), 512, 0, stream>>>(hsH, wqkvH, b_qkv, qkvO, O3, EMB);

  rope_reorg_kernel<<<dim3(SEQ / 64, NH), 256, 0, stream>>>(qkvO, cosp, sinp, Qp, Kp, Vt);

  // attn: 128-q blocks (8 waves), triple-buffered + T15 ping-pong + XCD swizzle. 512 blocks.
  attn_kernel<<<dim3(SEGLEN / 128, NH, NSEG), 512, 0, stream>>>(Qp, Kp, Vt, attnH);

  // proj GEMM: 128^2 tile, 2-phase counted-vmcnt schedule + XCD swizzle (320 blocks, 40/XCD)
  gemm128_kernel<<<dim3(EMB / 128, SEQ / 128), 256, 0, stream>>>(attnH, wprojH, b_proj, out, EMB, EMB);
}